// Round 5
// baseline (985.706 us; speedup 1.0000x reference)
//
#include <hip/hip_runtime.h>
#include <hip/hip_bf16.h>

#define B_ 256
#define T_ 512
#define I_ 128
#define H_ 256

typedef __bf16 bf16x8 __attribute__((ext_vector_type(8)));
typedef float  f32x4  __attribute__((ext_vector_type(4)));
typedef unsigned short u16;
typedef unsigned int   u32;

union U16x8Cast { uint4 v; bf16x8 b; };

__device__ inline u16 f2b(float f) {           // fp32 -> bf16 bits (RNE)
    union { __bf16 h; u16 u; } c; c.h = (__bf16)f; return c.u;
}
__device__ inline bf16x8 pack8(float4 lo, float4 hi) {
    bf16x8 f;
    f[0]=(__bf16)lo.x; f[1]=(__bf16)lo.y; f[2]=(__bf16)lo.z; f[3]=(__bf16)lo.w;
    f[4]=(__bf16)hi.x; f[5]=(__bf16)hi.y; f[6]=(__bf16)hi.z; f[7]=(__bf16)hi.w;
    return f;
}
__device__ inline uint2 pack4(float a, float b, float c, float d) {
    uint2 p;
    p.x = (u32)f2b(a) | ((u32)f2b(b) << 16);
    p.y = (u32)f2b(c) | ((u32)f2b(d) << 16);
    return p;
}
__device__ inline f32x4 b4_to_f32x4(uint2 u) {
    f32x4 r;
    r[0] = __uint_as_float(u.x << 16);
    r[1] = __uint_as_float(u.x & 0xFFFF0000u);
    r[2] = __uint_as_float(u.y << 16);
    r[3] = __uint_as_float(u.y & 0xFFFF0000u);
    return r;
}
__device__ inline bf16x8 asbf(uint4 u) { U16x8Cast c; c.v = u; return c.b; }
__device__ inline float fast_tanh(float x) {
    float e = __expf(2.f * x);
    float r = 1.f / (1.f + e);                 // v_rcp under -ffast-math-ish codegen
    return 1.f - 2.f * r;
}

// Raw workgroup barrier: LDS-drain only, NO vmcnt(0) drain of in-flight
// global prefetches (the __syncthreads fence would drain them every step).
#define WG_BARRIER() asm volatile("s_waitcnt lgkmcnt(0)\n\ts_barrier" ::: "memory")

// =====================================================================
// Kernel 0: pre-pack W_hh (fp32 [256][256]) into bf16 MFMA-A-fragment
// order: wpk[((wave*4+tau)*8+kap)*64 + lane] = 16B frag so the scan's
// weight load is a PURE coalesced dwordx4 (nothing to rematerialize).
// =====================================================================
__global__ __launch_bounds__(256) void prepack_whh(const float* __restrict__ W_hh,
                                                   uint4* __restrict__ wpk) {
    const int g    = (int)blockIdx.x * 256 + (int)threadIdx.x;  // 0..8191
    const int lane = g & 63;
    const int kap  = (g >> 6) & 7;
    const int tau  = (g >> 9) & 3;
    const int wv   = g >> 11;
    const int q    = lane >> 4;
    const int m    = lane & 15;
    const float* wr = W_hh + (size_t)(wv * 64 + tau * 16 + m) * H_ + kap * 32 + q * 8;
    U16x8Cast c; c.b = pack8(*(const float4*)wr, *(const float4*)(wr + 4));
    wpk[g] = c.v;
}

// =====================================================================
// Kernel 1 (MFMA GEMM): xw[t][b][n] = x[bT+t,:]*W_ih[n,:] + bias[n]
// m-tile enlarged 32 -> 128 per WG (W_ih re-fetch 512 MB -> 128 MB, 16
// concurrent x-loads per kap for MLP). A = W_ih, B = x so lane's f32x4 =
// 4 consecutive n -> LDS stage (2 passes of 64 t-rows) -> coalesced
// dwordx4 stores to [t][b][n] bf16.
// =====================================================================
#define LDST 264   // u16 stride of LDS tile row (528 B)
__global__ __launch_bounds__(256, 2) void xw_gemm_mfma(const float* __restrict__ x,
                                                       const float* __restrict__ W_ih,
                                                       const float* __restrict__ b_ih,
                                                       const float* __restrict__ b_hh,
                                                       u16* __restrict__ xw) {
    __shared__ u16 tile[64 * LDST];                // 33.8 KB

    const int tid  = (int)threadIdx.x;
    const int wave = tid >> 6;
    const int lane = tid & 63;
    const int q    = lane >> 4;
    const int ml   = lane & 15;
    const int m0   = (int)blockIdx.x * 128;        // 128 t-rows of one b
    const int b    = m0 >> 9;
    const int t0   = m0 & 511;
    const int n0   = wave * 64;

    // A-frags: W_ih[n = n0+tau*16+ml][k = kap*32+q*8 + 0..7]
    bf16x8 wA[4][4];
#pragma unroll
    for (int tau = 0; tau < 4; ++tau) {
        const float* wr = W_ih + (size_t)(n0 + tau * 16 + ml) * I_;
#pragma unroll
        for (int kap = 0; kap < 4; ++kap) {
            const int k0 = kap * 32 + q * 8;
            wA[tau][kap] = pack8(*(const float4*)(wr + k0), *(const float4*)(wr + k0 + 4));
        }
    }

    f32x4 acc[8][4];
#pragma unroll
    for (int mt = 0; mt < 8; ++mt)
#pragma unroll
        for (int tau = 0; tau < 4; ++tau) acc[mt][tau] = (f32x4)0.f;

#pragma unroll
    for (int kap = 0; kap < 4; ++kap) {
        bf16x8 xB[8];
#pragma unroll
        for (int mt = 0; mt < 8; ++mt) {
            const float* xr = x + (size_t)(m0 + mt * 16 + ml) * I_ + kap * 32 + q * 8;
            xB[mt] = pack8(*(const float4*)xr, *(const float4*)(xr + 4));
        }
#pragma unroll
        for (int mt = 0; mt < 8; ++mt)
#pragma unroll
            for (int tau = 0; tau < 4; ++tau)
                acc[mt][tau] = __builtin_amdgcn_mfma_f32_16x16x32_bf16(
                    wA[tau][kap], xB[mt], acc[mt][tau], 0, 0, 0);
    }

    float4 bias4[4];
#pragma unroll
    for (int tau = 0; tau < 4; ++tau) {
        const int n = n0 + tau * 16 + q * 4;
        float4 bi = *(const float4*)(b_ih + n);
        float4 bh = *(const float4*)(b_hh + n);
        bias4[tau] = make_float4(bi.x + bh.x, bi.y + bh.y, bi.z + bh.z, bi.w + bh.w);
    }

    // Epilogue: 2 passes x 64 t-rows through LDS, coalesced copy-out.
#pragma unroll
    for (int p = 0; p < 2; ++p) {
        if (p) __syncthreads();                    // tile reuse hazard
#pragma unroll
        for (int mt = 0; mt < 4; ++mt) {
            const int row = mt * 16 + ml;          // local t-row (C col = ml)
            const int mg  = p * 4 + mt;
#pragma unroll
            for (int tau = 0; tau < 4; ++tau) {
                uint2 pk = pack4(acc[mg][tau][0] + bias4[tau].x,
                                 acc[mg][tau][1] + bias4[tau].y,
                                 acc[mg][tau][2] + bias4[tau].z,
                                 acc[mg][tau][3] + bias4[tau].w);
                *(uint2*)(tile + row * LDST + n0 + tau * 16 + q * 4) = pk;
            }
        }
        __syncthreads();
        // copy-out: 16 lanes sweep one 512 B row; lane c copies bytes
        // [c*16, c*16+16) and [256+c*16, ...) -> conflict-free, coalesced.
#pragma unroll
        for (int s = 0; s < 4; ++s) {
            const int rr = s * 16 + (tid >> 4);
            const int c  = tid & 15;
            const uint4* srcp = (const uint4*)(tile + rr * LDST);
            uint4* dstp = (uint4*)(xw + ((size_t)(t0 + p * 64 + rr) * B_ + b) * H_);
            uint4 v0 = srcp[c];
            uint4 v1 = srcp[c + 16];
            dstp[c] = v0;
            dstp[c + 16] = v1;
        }
    }
}

// =====================================================================
// Kernel 2 (MFMA scan): 16 WGs x 256 thr (4 waves, 1/SIMD, 512-reg budget).
// Wave owns 64 H-rows as 32 pre-packed uint4 frags, PINNED via asm "+v"
// (remat impossible, pressure ~220 < 256 so no spill). h ping-pongs in LDS
// in B-frag order. Split accumulation chains (depth 4). Raw lgkm-only
// barrier keeps the xw prefetch in flight across steps.
// =====================================================================
__global__ __launch_bounds__(256, 1) void rnn_scan_mfma(const u16* __restrict__ xw,
                                                        const uint4* __restrict__ wpk,
                                                        const float* __restrict__ fc_w,
                                                        const float* __restrict__ fc_b,
                                                        float* __restrict__ out) {
    __shared__ __attribute__((aligned(16))) u16 hbuf[2][4096];  // 2 x 8 KB
    __shared__ float red[4][16];

    const int tid  = (int)threadIdx.x;
    const int wave = tid >> 6;          // 0..3
    const int lane = tid & 63;
    const int q    = lane >> 4;
    const int m    = lane & 15;
    const int b0   = (int)blockIdx.x * 16;

    // Pure coalesced loads of pre-packed W_hh frags, then pin to VGPRs.
    uint4 wfu[4][8];
#pragma unroll
    for (int tau = 0; tau < 4; ++tau)
#pragma unroll
        for (int kap = 0; kap < 8; ++kap)
            wfu[tau][kap] = wpk[((wave * 4 + tau) * 8 + kap) * 64 + lane];
#pragma unroll
    for (int tau = 0; tau < 4; ++tau)
#pragma unroll
        for (int kap = 0; kap < 8; ++kap)
            asm volatile("" : "+v"(wfu[tau][kap].x), "+v"(wfu[tau][kap].y),
                             "+v"(wfu[tau][kap].z), "+v"(wfu[tau][kap].w));

    // LDS write indices (u16 units) for C -> B-frag relayout
    int widx[4];
#pragma unroll
    for (int tau = 0; tau < 4; ++tau) {
        const int nbw = wave * 64 + tau * 16 + q * 4;
        widx[tau] = (nbw >> 5) * 512 + (((nbw >> 3) & 3) * 16 + m) * 8 + (nbw & 7);
    }

    // zero h buffer 0
    {
        uint4* p = (uint4*)&hbuf[0][0];
        const uint4 z = {0u, 0u, 0u, 0u};
        p[tid] = z; p[tid + 256] = z;
    }
    WG_BARRIER();

    // xw ([t][b][n]): lane reads 4 x uint2 at ((t*B_ + b0+m)*H_ + wave*64+tau*16+q*4)
    const u16* xwp = xw + (size_t)(b0 + m) * H_ + (wave * 64 + q * 4);
    const size_t tstride = (size_t)B_ * H_;
    f32x4 xwv[4];
#pragma unroll
    for (int tau = 0; tau < 4; ++tau)
        xwv[tau] = b4_to_f32x4(*(const uint2*)(xwp + tau * 16));

    int cur = 0;
    f32x4 accM[4];
    for (int t = 0; t < T_; ++t) {
        f32x4 accA[4], accB[4];
#pragma unroll
        for (int tau = 0; tau < 4; ++tau) { accA[tau] = xwv[tau]; accB[tau] = (f32x4)0.f; }
        if (t + 1 < T_) {                              // prefetch next step's xw
            const u16* pt = xwp + (size_t)(t + 1) * tstride;
#pragma unroll
            for (int tau = 0; tau < 4; ++tau)
                xwv[tau] = b4_to_f32x4(*(const uint2*)(pt + tau * 16));
        }

        const uint4* hb = (const uint4*)&hbuf[cur][0];
#pragma unroll
        for (int kap = 0; kap < 4; ++kap) {            // two parallel depth-4 chains
            U16x8Cast cA; cA.v = hb[kap * 64 + lane];
            U16x8Cast cB; cB.v = hb[(kap + 4) * 64 + lane];
#pragma unroll
            for (int tau = 0; tau < 4; ++tau) {
                accA[tau] = __builtin_amdgcn_mfma_f32_16x16x32_bf16(
                    asbf(wfu[tau][kap]), cA.b, accA[tau], 0, 0, 0);
                accB[tau] = __builtin_amdgcn_mfma_f32_16x16x32_bf16(
                    asbf(wfu[tau][kap + 4]), cB.b, accB[tau], 0, 0, 0);
            }
        }
#pragma unroll
        for (int tau = 0; tau < 4; ++tau) accM[tau] = accA[tau] + accB[tau];

        if (t == T_ - 1) break;                        // last h feeds fc only

        u16* wb = &hbuf[cur ^ 1][0];
#pragma unroll
        for (int tau = 0; tau < 4; ++tau) {
            uint2 pk = pack4(fast_tanh(accM[tau][0]), fast_tanh(accM[tau][1]),
                             fast_tanh(accM[tau][2]), fast_tanh(accM[tau][3]));
            *(uint2*)(wb + widx[tau]) = pk;
        }
        WG_BARRIER();
        cur ^= 1;
    }

    // fc head
    float4 fcw[4];
#pragma unroll
    for (int tau = 0; tau < 4; ++tau)
        fcw[tau] = *(const float4*)(fc_w + wave * 64 + tau * 16 + q * 4);

    float partial = 0.f;
#pragma unroll
    for (int tau = 0; tau < 4; ++tau) {
        partial += fast_tanh(accM[tau][0]) * fcw[tau].x;
        partial += fast_tanh(accM[tau][1]) * fcw[tau].y;
        partial += fast_tanh(accM[tau][2]) * fcw[tau].z;
        partial += fast_tanh(accM[tau][3]) * fcw[tau].w;
    }
    partial += __shfl_xor(partial, 16);
    partial += __shfl_xor(partial, 32);
    __syncthreads();
    if (lane < 16) red[wave][m] = partial;
    __syncthreads();
    if (tid < 16)
        out[b0 + tid] = red[0][tid] + red[1][tid] + red[2][tid] + red[3][tid] + fc_b[0];
}

// =====================================================================
extern "C" void kernel_launch(void* const* d_in, const int* in_sizes, int n_in,
                              void* d_out, int out_size, void* d_ws, size_t ws_size,
                              hipStream_t stream) {
    const float* x    = (const float*)d_in[0];
    const float* W_ih = (const float*)d_in[1];
    const float* W_hh = (const float*)d_in[2];
    const float* b_ih = (const float*)d_in[3];
    const float* b_hh = (const float*)d_in[4];
    const float* fc_w = (const float*)d_in[5];
    const float* fc_b = (const float*)d_in[6];
    float* out = (float*)d_out;

    // ws layout: [wpk: 128 KB][xw bf16 [T][B][H]: 64 MB]
    uint4* wpk = (uint4*)d_ws;
    u16* xwbuf = (u16*)((char*)d_ws + 8192 * sizeof(uint4));

    prepack_whh<<<32, 256, 0, stream>>>(W_hh, wpk);
    xw_gemm_mfma<<<(B_ * T_) / 128, 256, 0, stream>>>(x, W_ih, b_ih, b_hh, xwbuf);
    rnn_scan_mfma<<<B_ / 16, 256, 0, stream>>>(xwbuf, wpk, fc_w, fc_b, out);
}

// Round 6
// 850.460 us; speedup vs baseline: 1.1590x; 1.1590x over previous
//
#include <hip/hip_runtime.h>
#include <hip/hip_bf16.h>

#define B_ 256
#define T_ 512
#define I_ 128
#define H_ 256

typedef __bf16 bf16x8 __attribute__((ext_vector_type(8)));
typedef float  f32x4  __attribute__((ext_vector_type(4)));
typedef unsigned short u16;
typedef unsigned int   u32;

union U16x8Cast { uint4 v; bf16x8 b; };

__device__ inline u16 f2b(float f) {           // fp32 -> bf16 bits (RNE)
    union { __bf16 h; u16 u; } c; c.h = (__bf16)f; return c.u;
}
__device__ inline bf16x8 pack8(float4 lo, float4 hi) {
    bf16x8 f;
    f[0]=(__bf16)lo.x; f[1]=(__bf16)lo.y; f[2]=(__bf16)lo.z; f[3]=(__bf16)lo.w;
    f[4]=(__bf16)hi.x; f[5]=(__bf16)hi.y; f[6]=(__bf16)hi.z; f[7]=(__bf16)hi.w;
    return f;
}
__device__ inline uint2 pack4(float a, float b, float c, float d) {
    uint2 p;
    p.x = (u32)f2b(a) | ((u32)f2b(b) << 16);
    p.y = (u32)f2b(c) | ((u32)f2b(d) << 16);
    return p;
}
__device__ inline f32x4 b4_to_f32x4(uint2 u) {
    f32x4 r;
    r[0] = __uint_as_float(u.x << 16);
    r[1] = __uint_as_float(u.x & 0xFFFF0000u);
    r[2] = __uint_as_float(u.y << 16);
    r[3] = __uint_as_float(u.y & 0xFFFF0000u);
    return r;
}
__device__ inline bf16x8 asbf(uint4 u) { U16x8Cast c; c.v = u; return c.b; }
__device__ inline float fast_tanh(float x) {
    float e = __expf(2.f * x);
    float r = 1.f / (1.f + e);
    return 1.f - 2.f * r;
}

// LDS-drain-only workgroup barrier: keeps global prefetches in flight.
#define WG_BARRIER() asm volatile("s_waitcnt lgkmcnt(0)\n\ts_barrier" ::: "memory")

// =====================================================================
// Kernel 0: pre-pack W_hh into bf16 MFMA-A-fragment order.
// wpk[(rb*8+kap)*64 + lane] holds rows rb*16+(lane&15), k=kap*32+(lane>>4)*8+0..7
// =====================================================================
__global__ __launch_bounds__(256) void prepack_whh(const float* __restrict__ W_hh,
                                                   uint4* __restrict__ wpk) {
    const int g    = (int)blockIdx.x * 256 + (int)threadIdx.x;  // 0..8191
    const int lane = g & 63;
    const int kap  = (g >> 6) & 7;
    const int rb   = g >> 9;                       // row-block 0..15
    const int q    = lane >> 4;
    const int m    = lane & 15;
    const float* wr = W_hh + (size_t)(rb * 16 + m) * H_ + kap * 32 + q * 8;
    U16x8Cast c; c.b = pack8(*(const float4*)wr, *(const float4*)(wr + 4));
    wpk[g] = c.v;
}

// =====================================================================
// Kernel 1 (MFMA GEMM): xw[t][b][n] = x[bT+t,:]*W_ih[n,:] + bias[n]
// (unchanged from round 5: 128-row m-tile, coalesced [t][b][n] bf16 out)
// =====================================================================
#define LDST 264
__global__ __launch_bounds__(256, 2) void xw_gemm_mfma(const float* __restrict__ x,
                                                       const float* __restrict__ W_ih,
                                                       const float* __restrict__ b_ih,
                                                       const float* __restrict__ b_hh,
                                                       u16* __restrict__ xw) {
    __shared__ u16 tile[64 * LDST];

    const int tid  = (int)threadIdx.x;
    const int wave = tid >> 6;
    const int lane = tid & 63;
    const int q    = lane >> 4;
    const int ml   = lane & 15;
    const int m0   = (int)blockIdx.x * 128;
    const int b    = m0 >> 9;
    const int t0   = m0 & 511;
    const int n0   = wave * 64;

    bf16x8 wA[4][4];
#pragma unroll
    for (int tau = 0; tau < 4; ++tau) {
        const float* wr = W_ih + (size_t)(n0 + tau * 16 + ml) * I_;
#pragma unroll
        for (int kap = 0; kap < 4; ++kap) {
            const int k0 = kap * 32 + q * 8;
            wA[tau][kap] = pack8(*(const float4*)(wr + k0), *(const float4*)(wr + k0 + 4));
        }
    }

    f32x4 acc[8][4];
#pragma unroll
    for (int mt = 0; mt < 8; ++mt)
#pragma unroll
        for (int tau = 0; tau < 4; ++tau) acc[mt][tau] = (f32x4)0.f;

#pragma unroll
    for (int kap = 0; kap < 4; ++kap) {
        bf16x8 xB[8];
#pragma unroll
        for (int mt = 0; mt < 8; ++mt) {
            const float* xr = x + (size_t)(m0 + mt * 16 + ml) * I_ + kap * 32 + q * 8;
            xB[mt] = pack8(*(const float4*)xr, *(const float4*)(xr + 4));
        }
#pragma unroll
        for (int mt = 0; mt < 8; ++mt)
#pragma unroll
            for (int tau = 0; tau < 4; ++tau)
                acc[mt][tau] = __builtin_amdgcn_mfma_f32_16x16x32_bf16(
                    wA[tau][kap], xB[mt], acc[mt][tau], 0, 0, 0);
    }

    float4 bias4[4];
#pragma unroll
    for (int tau = 0; tau < 4; ++tau) {
        const int n = n0 + tau * 16 + q * 4;
        float4 bi = *(const float4*)(b_ih + n);
        float4 bh = *(const float4*)(b_hh + n);
        bias4[tau] = make_float4(bi.x + bh.x, bi.y + bh.y, bi.z + bh.z, bi.w + bh.w);
    }

#pragma unroll
    for (int p = 0; p < 2; ++p) {
        if (p) __syncthreads();
#pragma unroll
        for (int mt = 0; mt < 4; ++mt) {
            const int row = mt * 16 + ml;
            const int mg  = p * 4 + mt;
#pragma unroll
            for (int tau = 0; tau < 4; ++tau) {
                uint2 pk = pack4(acc[mg][tau][0] + bias4[tau].x,
                                 acc[mg][tau][1] + bias4[tau].y,
                                 acc[mg][tau][2] + bias4[tau].z,
                                 acc[mg][tau][3] + bias4[tau].w);
                *(uint2*)(tile + row * LDST + n0 + tau * 16 + q * 4) = pk;
            }
        }
        __syncthreads();
#pragma unroll
        for (int s = 0; s < 4; ++s) {
            const int rr = s * 16 + (tid >> 4);
            const int c  = tid & 15;
            const uint4* srcp = (const uint4*)(tile + rr * LDST);
            uint4* dstp = (uint4*)(xw + ((size_t)(t0 + p * 64 + rr) * B_ + b) * H_);
            uint4 v0 = srcp[c];
            uint4 v1 = srcp[c + 16];
            dstp[c] = v0;
            dstp[c + 16] = v1;
        }
    }
}

// =====================================================================
// Kernel 2 (MFMA scan): 16 WGs x 512 thr (8 waves = 2/SIMD: best measured
// TLP config, R4). Wave owns 32 H-rows (2 taus) as pre-packed pinned frags
// (64 VGPR/AGPR). Fixes vs R4/R5:
//  - depth-2 raw xw prefetch FIFO (issue-to-use ~2 steps >> 900-cyc HBM lat)
//  - lgkm-only barrier (prefetch stays in flight across steps)
//  - 4 independent depth-4 MFMA chains (halved dependent-MFMA latency)
// =====================================================================
__global__ __launch_bounds__(512, 2) void rnn_scan_mfma(const u16* __restrict__ xw,
                                                        const uint4* __restrict__ wpk,
                                                        const float* __restrict__ fc_w,
                                                        const float* __restrict__ fc_b,
                                                        float* __restrict__ out) {
    __shared__ __attribute__((aligned(16))) u16 hbuf[2][4096];  // 2 x 8 KB
    __shared__ float red[8][16];

    const int tid  = (int)threadIdx.x;
    const int wave = tid >> 6;          // 0..7
    const int lane = tid & 63;
    const int q    = lane >> 4;
    const int m    = lane & 15;
    const int b0   = (int)blockIdx.x * 16;

    // Pre-packed W_hh frags: rows rb = wave*2 + tau2. Pure coalesced loads, pinned.
    uint4 wfu[2][8];
#pragma unroll
    for (int tau2 = 0; tau2 < 2; ++tau2)
#pragma unroll
        for (int kap = 0; kap < 8; ++kap)
            wfu[tau2][kap] = wpk[((wave * 2 + tau2) * 8 + kap) * 64 + lane];
#pragma unroll
    for (int tau2 = 0; tau2 < 2; ++tau2)
#pragma unroll
        for (int kap = 0; kap < 8; ++kap)
            asm volatile("" : "+v"(wfu[tau2][kap].x), "+v"(wfu[tau2][kap].y),
                             "+v"(wfu[tau2][kap].z), "+v"(wfu[tau2][kap].w));

    // LDS write indices (u16 units) for C -> B-frag relayout
    int widx[2];
#pragma unroll
    for (int tau2 = 0; tau2 < 2; ++tau2) {
        const int nbw = wave * 32 + tau2 * 16 + q * 4;
        widx[tau2] = (nbw >> 5) * 512 + (((nbw >> 3) & 3) * 16 + m) * 8 + (nbw & 7);
    }

    // zero h buffer 0 (8 KB = 512 uint4)
    {
        uint4* p = (uint4*)&hbuf[0][0];
        const uint4 z = {0u, 0u, 0u, 0u};
        p[tid] = z;
    }
    WG_BARRIER();

    // xw ([t][b][n]); depth-2 raw prefetch FIFO: pf0 = step t, pf1 = step t+1
    const u16* xwp = xw + (size_t)(b0 + m) * H_ + (wave * 32 + q * 4);
    const size_t tstride = (size_t)B_ * H_;
    uint2 pf0[2], pf1[2];
#pragma unroll
    for (int tau2 = 0; tau2 < 2; ++tau2) {
        pf0[tau2] = *(const uint2*)(xwp + tau2 * 16);
        pf1[tau2] = *(const uint2*)(xwp + tstride + tau2 * 16);
    }

    int cur = 0;
    f32x4 accM[2];
    for (int t = 0; t < T_; ++t) {
        f32x4 accA[2], accB[2];
        accA[0] = b4_to_f32x4(pf0[0]);
        accA[1] = b4_to_f32x4(pf0[1]);
        accB[0] = (f32x4)0.f;
        accB[1] = (f32x4)0.f;
        pf0[0] = pf1[0];
        pf0[1] = pf1[1];
        if (t + 2 < T_) {                              // issue load for t+2
            const u16* pt = xwp + (size_t)(t + 2) * tstride;
            pf1[0] = *(const uint2*)(pt);
            pf1[1] = *(const uint2*)(pt + 16);
        }

        const uint4* hb = (const uint4*)&hbuf[cur][0];
#pragma unroll
        for (int kap = 0; kap < 4; ++kap) {            // 4 indep depth-4 chains
            U16x8Cast cA; cA.v = hb[kap * 64 + lane];
            U16x8Cast cB; cB.v = hb[(kap + 4) * 64 + lane];
            accA[0] = __builtin_amdgcn_mfma_f32_16x16x32_bf16(asbf(wfu[0][kap]),     cA.b, accA[0], 0, 0, 0);
            accA[1] = __builtin_amdgcn_mfma_f32_16x16x32_bf16(asbf(wfu[1][kap]),     cA.b, accA[1], 0, 0, 0);
            accB[0] = __builtin_amdgcn_mfma_f32_16x16x32_bf16(asbf(wfu[0][kap + 4]), cB.b, accB[0], 0, 0, 0);
            accB[1] = __builtin_amdgcn_mfma_f32_16x16x32_bf16(asbf(wfu[1][kap + 4]), cB.b, accB[1], 0, 0, 0);
        }
        accM[0] = accA[0] + accB[0];
        accM[1] = accA[1] + accB[1];

        if (t == T_ - 1) break;                        // last h feeds fc only

        u16* wb = &hbuf[cur ^ 1][0];
#pragma unroll
        for (int tau2 = 0; tau2 < 2; ++tau2) {
            uint2 pk = pack4(fast_tanh(accM[tau2][0]), fast_tanh(accM[tau2][1]),
                             fast_tanh(accM[tau2][2]), fast_tanh(accM[tau2][3]));
            *(uint2*)(wb + widx[tau2]) = pk;
        }
        WG_BARRIER();
        cur ^= 1;
    }

    // fc head: out[b] = sum_n tanh(h)[n] * fc_w[n] + fc_b
    float4 fcw[2];
#pragma unroll
    for (int tau2 = 0; tau2 < 2; ++tau2)
        fcw[tau2] = *(const float4*)(fc_w + wave * 32 + tau2 * 16 + q * 4);

    float partial = 0.f;
#pragma unroll
    for (int tau2 = 0; tau2 < 2; ++tau2) {
        partial += fast_tanh(accM[tau2][0]) * fcw[tau2].x;
        partial += fast_tanh(accM[tau2][1]) * fcw[tau2].y;
        partial += fast_tanh(accM[tau2][2]) * fcw[tau2].z;
        partial += fast_tanh(accM[tau2][3]) * fcw[tau2].w;
    }
    partial += __shfl_xor(partial, 16);
    partial += __shfl_xor(partial, 32);
    __syncthreads();
    if (lane < 16) red[wave][m] = partial;
    __syncthreads();
    if (tid < 16) {
        float s = red[0][tid] + red[1][tid] + red[2][tid] + red[3][tid]
                + red[4][tid] + red[5][tid] + red[6][tid] + red[7][tid];
        out[b0 + tid] = s + fc_b[0];
    }
}

// =====================================================================
extern "C" void kernel_launch(void* const* d_in, const int* in_sizes, int n_in,
                              void* d_out, int out_size, void* d_ws, size_t ws_size,
                              hipStream_t stream) {
    const float* x    = (const float*)d_in[0];
    const float* W_ih = (const float*)d_in[1];
    const float* W_hh = (const float*)d_in[2];
    const float* b_ih = (const float*)d_in[3];
    const float* b_hh = (const float*)d_in[4];
    const float* fc_w = (const float*)d_in[5];
    const float* fc_b = (const float*)d_in[6];
    float* out = (float*)d_out;

    // ws layout: [wpk: 128 KB][xw bf16 [T][B][H]: 64 MB]
    uint4* wpk = (uint4*)d_ws;
    u16* xwbuf = (u16*)((char*)d_ws + 8192 * sizeof(uint4));

    prepack_whh<<<32, 256, 0, stream>>>(W_hh, wpk);
    xw_gemm_mfma<<<(B_ * T_) / 128, 256, 0, stream>>>(x, W_ih, b_ih, b_hh, xwbuf);
    rnn_scan_mfma<<<B_ / 16, 512, 0, stream>>>(xwbuf, wpk, fc_w, fc_b, out);
}